// Round 11
// baseline (156.647 us; speedup 1.0000x reference)
//
#include <hip/hip_runtime.h>

#define D 128
#define CBITS 8    // 256 nodes per coarse bucket; NBC<=256 for N<=65536

typedef __attribute__((ext_vector_type(8))) short short8;
typedef __attribute__((ext_vector_type(4))) float f32x4;

__device__ __forceinline__ unsigned short f2b(float f) {
    unsigned u = __builtin_bit_cast(unsigned, f);
    u += 0x7fffu + ((u >> 16) & 1u);           // round-to-nearest-even
    return (unsigned short)(u >> 16);
}
__device__ __forceinline__ float b2f(unsigned short b) {
    unsigned u = ((unsigned)b) << 16;
    return __builtin_bit_cast(float, u);
}

// ---------------- combined prep: cast x -> Acat1[:,128:], W->WT bf16, zero counters --------

__global__ __launch_bounds__(256) void prep_kernel(
    const float* __restrict__ x, unsigned short* __restrict__ acat, int nCast, int n8,
    const float* __restrict__ W1l, const float* __restrict__ W1r,
    const float* __restrict__ W2l, const float* __restrict__ W2r,
    unsigned short* __restrict__ WT1, unsigned short* __restrict__ WT2,
    int4* __restrict__ zeroPtr, int* __restrict__ offsets, int nnodes, int E) {
    const int b = blockIdx.x;
    if (b < nCast) {
        int g = b * 256 + threadIdx.x;
        if (g < n8) {
            int row = g >> 4, chunk = g & 15;
            const float4 v0 = *reinterpret_cast<const float4*>(x + (size_t)g * 8);
            const float4 v1 = *reinterpret_cast<const float4*>(x + (size_t)g * 8 + 4);
            short8 r;
            r[0] = (short)f2b(v0.x); r[1] = (short)f2b(v0.y); r[2] = (short)f2b(v0.z); r[3] = (short)f2b(v0.w);
            r[4] = (short)f2b(v1.x); r[5] = (short)f2b(v1.y); r[6] = (short)f2b(v1.z); r[7] = (short)f2b(v1.w);
            *reinterpret_cast<short8*>(acat + (size_t)row * 256 + 128 + chunk * 8) = r;
        }
    } else if (b < nCast + 256) {
        int bb = b - nCast;
        int layer = bb >> 7;
        int j = bb & 127;
        int k = threadIdx.x;  // 0..255
        const float* Wl = layer ? W2l : W1l;
        const float* Wr = layer ? W2r : W1r;
        unsigned short* WT = layer ? WT2 : WT1;
        float v = (k < 128) ? Wl[k * D + j] : Wr[(k - 128) * D + j];
        WT[(size_t)j * 256 + k] = f2b(v);
    } else {
        if (threadIdx.x < 128) zeroPtr[threadIdx.x] = make_int4(0, 0, 0, 0);
        if (threadIdx.x == 0) offsets[nnodes] = E;
    }
}

// ---------------- CSR build: zero per-edge global atomics ----------------

__global__ __launch_bounds__(256) void bucket_count_kernel(
    const int* __restrict__ dst, int* __restrict__ bucketCnt, int E) {
    __shared__ int hist[256];
    const int t = threadIdx.x;
    hist[t] = 0;
    __syncthreads();
    const int base = blockIdx.x * 4096;
#pragma unroll
    for (int i = 0; i < 16; ++i) {
        int e = base + i * 256 + t;
        if (e < E) atomicAdd(&hist[dst[e] >> CBITS], 1);
    }
    __syncthreads();
    if (hist[t]) atomicAdd(&bucketCnt[t], hist[t]);
}

// bin_coarse: inline 256-wide scan of bucketCnt, LDS-privatized reservation
// (R4 lesson: never 1 global atomic/edge). Staging packed: src | dstLocal<<16 (N<=65536).
__global__ __launch_bounds__(256) void bin_coarse_kernel(
    const int* __restrict__ src, const int* __restrict__ dst,
    const int* __restrict__ bucketCnt, int* __restrict__ cursorA,
    int* __restrict__ staging, int E) {

    __shared__ int hist[256];
    __shared__ int lcur[256];
    const int t = threadIdx.x;

    // inclusive scan of bucketCnt in lcur -> myBase (exclusive)
    int cnt = bucketCnt[t];
    lcur[t] = cnt;
    __syncthreads();
    for (int d = 1; d < 256; d <<= 1) {
        int u = (t >= d) ? lcur[t - d] : 0;
        __syncthreads();
        lcur[t] += u;
        __syncthreads();
    }
    const int myBase = lcur[t] - cnt;
    __syncthreads();

    hist[t] = 0;
    __syncthreads();

    const int base = blockIdx.x * 4096;
    int sreg[16], dreg[16];
#pragma unroll
    for (int i = 0; i < 16; ++i) {
        int e = base + i * 256 + t;
        int s = 0, d = -1;
        if (e < E) {
            s = src[e]; d = dst[e];
            atomicAdd(&hist[d >> CBITS], 1);
        }
        sreg[i] = s; dreg[i] = d;
    }
    __syncthreads();
    {
        int h = hist[t];
        lcur[t] = myBase + (h ? atomicAdd(&cursorA[t], h) : 0);
    }
    __syncthreads();
#pragma unroll
    for (int i = 0; i < 16; ++i) {
        if (dreg[i] >= 0) {
            int p = atomicAdd(&lcur[dreg[i] >> CBITS], 1);   // LDS atomic
            staging[p] = sreg[i] | ((dreg[i] & 255) << 16);  // packed 24-bit
        }
    }
}

// bucket_build: one block per bucket; re-derives bases via inline scan, then
// per-node hist + scan + ordered scatter, all in LDS.
__global__ __launch_bounds__(256) void bucket_build_kernel(
    const int* __restrict__ staging, const int* __restrict__ bucketCnt,
    int* __restrict__ offsets, int* __restrict__ csr, int nnodes) {

    __shared__ int A1[256];
    __shared__ int A2[256];
    const int t = threadIdx.x;
    const int b = blockIdx.x;

    int cnt = bucketCnt[t];
    A1[t] = cnt;
    __syncthreads();
    for (int d = 1; d < 256; d <<= 1) {
        int u = (t >= d) ? A1[t - d] : 0;
        __syncthreads();
        A1[t] += u;
        __syncthreads();
    }
    const int end  = A1[b];
    const int base = end - bucketCnt[b];
    __syncthreads();

    A1[t] = 0;
    __syncthreads();
    for (int i = base + t; i < end; i += 256)
        atomicAdd(&A1[(staging[i] >> 16) & 255], 1);
    __syncthreads();
    A2[t] = A1[t];
    __syncthreads();
    for (int d = 1; d < 256; d <<= 1) {
        int u = (t >= d) ? A2[t - d] : 0;
        __syncthreads();
        A2[t] += u;
        __syncthreads();
    }
    const int excl = A2[t] - A1[t];
    const int node = (b << CBITS) + t;
    if (node < nnodes) offsets[node] = base + excl;
    __syncthreads();
    A1[t] = base + excl;          // reuse A1 as cursor
    __syncthreads();
    for (int i = base + t; i < end; i += 256) {
        int p = staging[i];
        int c = atomicAdd(&A1[(p >> 16) & 255], 1);          // LDS atomic
        csr[c] = p & 0xFFFF;
    }
}

// ---------------- mean aggregation: channel-quartered gather ----------------
// R10 analysis: gather is L2-miss-bound (12.8MB table >> 4MB/XCD L2, FETCH 75MB).
// Split feature dim into 4 x 32-ch quarters (64B): each 3.2MB slice is L2-resident
// per XCD; quarter-major grid keeps the whole machine on one slice at a time.
// 4 lanes x 16B per node, 64 nodes/block, x8 unroll.

__global__ __launch_bounds__(256) void aggregate_kernel(
    const unsigned short* __restrict__ xin,   // row stride 256 (pre-offset +128)
    const int* __restrict__ offsets, const int* __restrict__ csr,
    unsigned short* __restrict__ out,         // row stride 256 (offset 0)
    int nnodes, int nodeBlocks) {
    const int q  = blockIdx.x / nodeBlocks;   // 0..3, quarter-major dispatch
    const int nb = blockIdx.x - q * nodeBlocks;
    const int node = nb * 64 + (threadIdx.x >> 2);
    const int l4 = threadIdx.x & 3;
    if (node >= nnodes) return;
    const int coff = q * 32 + l4 * 8;         // channel offset (ushorts)
    const unsigned short* xq = xin + coff;
    int lo = offsets[node], hi = offsets[node + 1];
    float acc[8] = {0.f, 0.f, 0.f, 0.f, 0.f, 0.f, 0.f, 0.f};
    int k = lo;
    for (; k + 8 <= hi; k += 8) {
        int s[8];
        short8 v[8];
#pragma unroll
        for (int u = 0; u < 8; ++u) s[u] = csr[k + u];
#pragma unroll
        for (int u = 0; u < 8; ++u)
            v[u] = *reinterpret_cast<const short8*>(xq + (size_t)s[u] * 256);
#pragma unroll
        for (int u = 0; u < 8; ++u)
#pragma unroll
            for (int i = 0; i < 8; ++i) acc[i] += b2f((unsigned short)v[u][i]);
    }
    for (; k < hi; ++k) {
        int s = csr[k];
        const short8 v = *reinterpret_cast<const short8*>(xq + (size_t)s * 256);
#pragma unroll
        for (int i = 0; i < 8; ++i) acc[i] += b2f((unsigned short)v[i]);
    }
    float inv = 1.0f / fmaxf((float)(hi - lo), 1.0f);
    short8 r;
#pragma unroll
    for (int i = 0; i < 8; ++i) r[i] = (short)f2b(acc[i] * inv);
    *reinterpret_cast<short8*>(out + (size_t)node * 256 + coff) = r;
}

// ---------------- fused SAGE linear via MFMA (+ optional head epilogue) ----------------
// WT staged in 64KB swizzled LDS (R10: killed the per-wave B re-read); 32 rows/wave.

template <bool RELU, bool HEAD>
__global__ __launch_bounds__(256) void sage_mfma_kernel(
    const unsigned short* __restrict__ Acat, const unsigned short* __restrict__ WT,
    const float* __restrict__ bias, unsigned short* __restrict__ hout, int out_stride,
    const float* __restrict__ Wfc, const float* __restrict__ bfc,
    float* __restrict__ outf, int nnodes) {

    __shared__ unsigned short Blds[128 * 256];   // 64KB, 16B-unit swizzle: c ^= row&7
    const int tid = threadIdx.x;

    {   // stage WT -> LDS (coalesced global, swizzled LDS)
        const short8* wsrc = reinterpret_cast<const short8*>(WT);
#pragma unroll
        for (int it = 0; it < 16; ++it) {
            int u = it * 256 + tid;                // 16B unit: 4096 total
            int row = u >> 5, c = u & 31;
            int cs = c ^ (row & 7);
            *reinterpret_cast<short8*>(
                reinterpret_cast<char*>(Blds) + row * 512 + cs * 16) = wsrc[u];
        }
    }
    __syncthreads();

    const int w = tid >> 6, l = tid & 63;
    const int r16 = l & 15, g = l >> 4;
    const int rowbase = blockIdx.x * 128 + w * 32;

    f32x4 acc[2][8];
#pragma unroll
    for (int j = 0; j < 8; ++j) {
        float bj = bias[j * 16 + r16];
        acc[0][j] = (f32x4){bj, bj, bj, bj};
        acc[1][j] = (f32x4){bj, bj, bj, bj};
    }

    const unsigned short* ap0 = Acat + (size_t)(rowbase + r16) * 256 + g * 8;
    const unsigned short* ap1 = ap0 + 16 * 256;

#pragma unroll
    for (int ks = 0; ks < 8; ++ks) {
        const short8 a0 = *reinterpret_cast<const short8*>(ap0 + ks * 32);
        const short8 a1 = *reinterpret_cast<const short8*>(ap1 + ks * 32);
        const int cs = ((ks * 4 + g) ^ (r16 & 7)) * 16;
#pragma unroll
        for (int j = 0; j < 8; ++j) {
            const short8 b = *reinterpret_cast<const short8*>(
                reinterpret_cast<const char*>(Blds) + (j * 16 + r16) * 512 + cs);
            acc[0][j] = __builtin_amdgcn_mfma_f32_16x16x32_bf16(a0, b, acc[0][j], 0, 0, 0);
            acc[1][j] = __builtin_amdgcn_mfma_f32_16x16x32_bf16(a1, b, acc[1][j], 0, 0, 0);
        }
    }

#pragma unroll
    for (int rb = 0; rb < 2; ++rb) {
        float ss[4] = {0.f, 0.f, 0.f, 0.f};
#pragma unroll
        for (int j = 0; j < 8; ++j)
#pragma unroll
            for (int i = 0; i < 4; ++i) ss[i] += acc[rb][j][i] * acc[rb][j][i];
#pragma unroll
        for (int m = 1; m < 16; m <<= 1)
#pragma unroll
            for (int i = 0; i < 4; ++i) ss[i] += __shfl_xor(ss[i], m, 64);

        if (!HEAD) {
#pragma unroll
            for (int i = 0; i < 4; ++i) {
                int row = rowbase + rb * 16 + g * 4 + i;
                if (row >= nnodes) continue;
                float sc = 1.0f / fmaxf(sqrtf(ss[i]), 1e-12f);
#pragma unroll
                for (int j = 0; j < 8; ++j) {
                    float v = acc[rb][j][i] * sc;
                    if (RELU) v = fmaxf(v, 0.f);
                    hout[(size_t)row * out_stride + j * 16 + r16] = f2b(v);
                }
            }
        } else {
            float w0[8], w1[8];
#pragma unroll
            for (int j = 0; j < 8; ++j) {
                const float2 wv = *reinterpret_cast<const float2*>(Wfc + (j * 16 + r16) * 2);
                w0[j] = wv.x; w1[j] = wv.y;
            }
            const float b0 = bfc[0], b1 = bfc[1];
#pragma unroll
            for (int i = 0; i < 4; ++i) {
                float sc = 1.0f / fmaxf(sqrtf(ss[i]), 1e-12f);
                float l0 = 0.f, l1 = 0.f;
#pragma unroll
                for (int j = 0; j < 8; ++j) {
                    float v = acc[rb][j][i] * sc;
                    l0 = fmaf(v, w0[j], l0);
                    l1 = fmaf(v, w1[j], l1);
                }
#pragma unroll
                for (int m = 1; m < 16; m <<= 1) {
                    l0 += __shfl_xor(l0, m, 64);
                    l1 += __shfl_xor(l1, m, 64);
                }
                int row = rowbase + rb * 16 + g * 4 + i;
                if (r16 == 0 && row < nnodes) {
                    float d0 = l0 + b0, d1 = l1 + b1;
                    float mx = fmaxf(d0, d1);
                    float e0 = expf(d0 - mx), e1 = expf(d1 - mx);
                    float inv = 1.0f / (e0 + e1);
                    outf[(size_t)row * 2]     = e0 * inv;
                    outf[(size_t)row * 2 + 1] = e1 * inv;
                }
            }
        }
    }
}

// ---------------- launch ----------------

extern "C" void kernel_launch(void* const* d_in, const int* in_sizes, int n_in,
                              void* d_out, int out_size, void* d_ws, size_t ws_size,
                              hipStream_t stream) {
    const float* x   = (const float*)d_in[0];
    const int*   ei  = (const int*)d_in[1];
    const float* W1l = (const float*)d_in[2];
    const float* b1l = (const float*)d_in[3];
    const float* W1r = (const float*)d_in[4];
    const float* W2l = (const float*)d_in[5];
    const float* b2l = (const float*)d_in[6];
    const float* W2r = (const float*)d_in[7];
    const float* Wfc = (const float*)d_in[8];
    const float* bfc = (const float*)d_in[9];

    const int N = in_sizes[0] / D;
    const int E = in_sizes[1] / 2;
    const int* src = ei;        // edge_index[0]
    const int* dst = ei + E;    // edge_index[1]
    const int NBC = (N + (1 << CBITS) - 1) >> CBITS;     // coarse buckets (196), <=256

    // workspace: bf16 feature tables first (16B aligned), ints after
    unsigned short* Acat1 = (unsigned short*)d_ws;        // N x 256 : [agg1 | xb]
    unsigned short* Acat2 = Acat1 + (size_t)N * 256;      // N x 256 : [agg2 | h1]
    int* staging          = (int*)Acat2;                  // E ints (dead until mfma1; consumed before)
    unsigned short* WT1   = Acat2 + (size_t)N * 256;      // 128 x 256
    unsigned short* WT2   = WT1 + 128 * 256;              // 128 x 256
    int* bucketCnt  = (int*)(WT2 + 128 * 256);            // 256 } zeroed together (512 ints)
    int* cursorA    = bucketCnt + 256;                    // 256 }
    int* offsets    = cursorA + 256;                      // N+1
    int* csr        = offsets + N + 1;                    // E

    const int nCast = (N * 16 + 255) / 256;
    const int nodeBlocks = (N + 63) / 64;

    // prep: cast x into Acat1[:,128:], transpose weights, zero counters, offsets[N]=E
    prep_kernel<<<nCast + 256 + 1, 256, 0, stream>>>(
        x, Acat1, nCast, N * 16, W1l, W1r, W2l, W2r, WT1, WT2,
        (int4*)bucketCnt, offsets, N, E);

    // CSR build: zero per-edge global atomics, scans inlined, packed staging
    bucket_count_kernel<<<(E + 4095) / 4096, 256, 0, stream>>>(dst, bucketCnt, E);
    bin_coarse_kernel<<<(E + 4095) / 4096, 256, 0, stream>>>(src, dst, bucketCnt, cursorA, staging, E);
    bucket_build_kernel<<<NBC, 256, 0, stream>>>(staging, bucketCnt, offsets, csr, N);

    // layer 1: agg(xb) -> Acat1[:,0:128]; h1 = relu(l2norm(...)) -> Acat2[:,128:256]
    aggregate_kernel<<<nodeBlocks * 4, 256, 0, stream>>>(Acat1 + 128, offsets, csr, Acat1, N, nodeBlocks);
    sage_mfma_kernel<true, false><<<(N + 127) / 128, 256, 0, stream>>>(
        Acat1, WT1, b1l, Acat2 + 128, 256, nullptr, nullptr, nullptr, N);

    // layer 2: agg(h1) -> Acat2[:,0:128]; head fused: softmax(l2norm(...)@Wfc+bfc) -> d_out
    aggregate_kernel<<<nodeBlocks * 4, 256, 0, stream>>>(Acat2 + 128, offsets, csr, Acat2, N, nodeBlocks);
    sage_mfma_kernel<false, true><<<(N + 127) / 128, 256, 0, stream>>>(
        Acat2, WT2, b2l, nullptr, 0, Wfc, bfc, (float*)d_out, N);
}

// Round 12
// 133.240 us; speedup vs baseline: 1.1757x; 1.1757x over previous
//
#include <hip/hip_runtime.h>

#define D 128
#define CBITS 8    // 256 nodes per coarse bucket; NBC<=256 for N<=65536

typedef __attribute__((ext_vector_type(8))) short short8;
typedef __attribute__((ext_vector_type(4))) float f32x4;

__device__ __forceinline__ unsigned short f2b(float f) {
    unsigned u = __builtin_bit_cast(unsigned, f);
    u += 0x7fffu + ((u >> 16) & 1u);           // round-to-nearest-even
    return (unsigned short)(u >> 16);
}
__device__ __forceinline__ float b2f(unsigned short b) {
    unsigned u = ((unsigned)b) << 16;
    return __builtin_bit_cast(float, u);
}

// ---------------- combined prep: cast x -> Acat1[:,128:], W->WT bf16, zero counters --------

__global__ __launch_bounds__(256) void prep_kernel(
    const float* __restrict__ x, unsigned short* __restrict__ acat, int nCast, int n8,
    const float* __restrict__ W1l, const float* __restrict__ W1r,
    const float* __restrict__ W2l, const float* __restrict__ W2r,
    unsigned short* __restrict__ WT1, unsigned short* __restrict__ WT2,
    int4* __restrict__ zeroPtr, int* __restrict__ offsets, int nnodes, int E) {
    const int b = blockIdx.x;
    if (b < nCast) {
        int g = b * 256 + threadIdx.x;
        if (g < n8) {
            int row = g >> 4, chunk = g & 15;
            const float4 v0 = *reinterpret_cast<const float4*>(x + (size_t)g * 8);
            const float4 v1 = *reinterpret_cast<const float4*>(x + (size_t)g * 8 + 4);
            short8 r;
            r[0] = (short)f2b(v0.x); r[1] = (short)f2b(v0.y); r[2] = (short)f2b(v0.z); r[3] = (short)f2b(v0.w);
            r[4] = (short)f2b(v1.x); r[5] = (short)f2b(v1.y); r[6] = (short)f2b(v1.z); r[7] = (short)f2b(v1.w);
            *reinterpret_cast<short8*>(acat + (size_t)row * 256 + 128 + chunk * 8) = r;
        }
    } else if (b < nCast + 256) {
        int bb = b - nCast;
        int layer = bb >> 7;
        int j = bb & 127;
        int k = threadIdx.x;  // 0..255
        const float* Wl = layer ? W2l : W1l;
        const float* Wr = layer ? W2r : W1r;
        unsigned short* WT = layer ? WT2 : WT1;
        float v = (k < 128) ? Wl[k * D + j] : Wr[(k - 128) * D + j];
        WT[(size_t)j * 256 + k] = f2b(v);
    } else {
        if (threadIdx.x < 128) zeroPtr[threadIdx.x] = make_int4(0, 0, 0, 0);
        if (threadIdx.x == 0) offsets[nnodes] = E;
    }
}

// ---------------- CSR build: zero per-edge global atomics ----------------

__global__ __launch_bounds__(256) void bucket_count_kernel(
    const int* __restrict__ dst, int* __restrict__ bucketCnt, int E) {
    __shared__ int hist[256];
    const int t = threadIdx.x;
    hist[t] = 0;
    __syncthreads();
    const int base = blockIdx.x * 4096;
#pragma unroll
    for (int i = 0; i < 16; ++i) {
        int e = base + i * 256 + t;
        if (e < E) atomicAdd(&hist[dst[e] >> CBITS], 1);
    }
    __syncthreads();
    if (hist[t]) atomicAdd(&bucketCnt[t], hist[t]);
}

// bin_coarse: inline 256-wide scan of bucketCnt, LDS-privatized reservation
// (R4 lesson: never 1 global atomic/edge). Staging packed: src | dstLocal<<16.
__global__ __launch_bounds__(256) void bin_coarse_kernel(
    const int* __restrict__ src, const int* __restrict__ dst,
    const int* __restrict__ bucketCnt, int* __restrict__ cursorA,
    int* __restrict__ staging, int E) {

    __shared__ int hist[256];
    __shared__ int lcur[256];
    const int t = threadIdx.x;

    int cnt = bucketCnt[t];
    lcur[t] = cnt;
    __syncthreads();
    for (int d = 1; d < 256; d <<= 1) {
        int u = (t >= d) ? lcur[t - d] : 0;
        __syncthreads();
        lcur[t] += u;
        __syncthreads();
    }
    const int myBase = lcur[t] - cnt;
    __syncthreads();

    hist[t] = 0;
    __syncthreads();

    const int base = blockIdx.x * 4096;
    int sreg[16], dreg[16];
#pragma unroll
    for (int i = 0; i < 16; ++i) {
        int e = base + i * 256 + t;
        int s = 0, d = -1;
        if (e < E) {
            s = src[e]; d = dst[e];
            atomicAdd(&hist[d >> CBITS], 1);
        }
        sreg[i] = s; dreg[i] = d;
    }
    __syncthreads();
    {
        int h = hist[t];
        lcur[t] = myBase + (h ? atomicAdd(&cursorA[t], h) : 0);
    }
    __syncthreads();
#pragma unroll
    for (int i = 0; i < 16; ++i) {
        if (dreg[i] >= 0) {
            int p = atomicAdd(&lcur[dreg[i] >> CBITS], 1);   // LDS atomic
            staging[p] = sreg[i] | ((dreg[i] & 255) << 16);  // packed 24-bit
        }
    }
}

// bucket_build: one block per bucket; re-derives bases via inline scan, then
// per-node hist + scan + ordered scatter, all in LDS.
__global__ __launch_bounds__(256) void bucket_build_kernel(
    const int* __restrict__ staging, const int* __restrict__ bucketCnt,
    int* __restrict__ offsets, int* __restrict__ csr, int nnodes) {

    __shared__ int A1[256];
    __shared__ int A2[256];
    const int t = threadIdx.x;
    const int b = blockIdx.x;

    int cnt = bucketCnt[t];
    A1[t] = cnt;
    __syncthreads();
    for (int d = 1; d < 256; d <<= 1) {
        int u = (t >= d) ? A1[t - d] : 0;
        __syncthreads();
        A1[t] += u;
        __syncthreads();
    }
    const int end  = A1[b];
    const int base = end - bucketCnt[b];
    __syncthreads();

    A1[t] = 0;
    __syncthreads();
    for (int i = base + t; i < end; i += 256)
        atomicAdd(&A1[(staging[i] >> 16) & 255], 1);
    __syncthreads();
    A2[t] = A1[t];
    __syncthreads();
    for (int d = 1; d < 256; d <<= 1) {
        int u = (t >= d) ? A2[t - d] : 0;
        __syncthreads();
        A2[t] += u;
        __syncthreads();
    }
    const int excl = A2[t] - A1[t];
    const int node = (b << CBITS) + t;
    if (node < nnodes) offsets[node] = base + excl;
    __syncthreads();
    A1[t] = base + excl;          // reuse A1 as cursor
    __syncthreads();
    for (int i = base + t; i < end; i += 256) {
        int p = staging[i];
        int c = atomicAdd(&A1[(p >> 16) & 255], 1);          // LDS atomic
        csr[c] = p & 0xFFFF;
    }
}

// ---------------- mean aggregation (bf16 gather, f32 accumulate) ----------------
// R10 form: 16 nodes/block (max TLP), 16 lanes x 16B per node, x8 unroll.
// R11 lesson: do NOT shrink gather payload below the 128B line (fetch amplification).

__global__ __launch_bounds__(256) void aggregate_kernel(
    const unsigned short* __restrict__ xin,   // row stride 256 (pre-offset +128)
    const int* __restrict__ offsets, const int* __restrict__ csr,
    unsigned short* __restrict__ out,         // row stride 256 (offset 0)
    int nnodes) {
    int node = blockIdx.x * 16 + (threadIdx.x >> 4);
    int l16 = threadIdx.x & 15;
    if (node >= nnodes) return;
    int lo = offsets[node], hi = offsets[node + 1];
    float acc[8] = {0.f, 0.f, 0.f, 0.f, 0.f, 0.f, 0.f, 0.f};
    int k = lo;
    for (; k + 8 <= hi; k += 8) {
        int s[8];
        short8 v[8];
#pragma unroll
        for (int u = 0; u < 8; ++u) s[u] = csr[k + u];
#pragma unroll
        for (int u = 0; u < 8; ++u)
            v[u] = *reinterpret_cast<const short8*>(xin + (size_t)s[u] * 256 + l16 * 8);
#pragma unroll
        for (int u = 0; u < 8; ++u)
#pragma unroll
            for (int i = 0; i < 8; ++i) acc[i] += b2f((unsigned short)v[u][i]);
    }
    for (; k < hi; ++k) {
        int s = csr[k];
        const short8 v = *reinterpret_cast<const short8*>(xin + (size_t)s * 256 + l16 * 8);
#pragma unroll
        for (int i = 0; i < 8; ++i) acc[i] += b2f((unsigned short)v[i]);
    }
    float inv = 1.0f / fmaxf((float)(hi - lo), 1.0f);
    short8 r;
#pragma unroll
    for (int i = 0; i < 8; ++i) r[i] = (short)f2b(acc[i] * inv);
    *reinterpret_cast<short8*>(out + (size_t)node * 256 + l16 * 8) = r;
}

// ---------------- fused SAGE linear via MFMA (+ optional head epilogue) ----------------
// WT staged in 64KB swizzled LDS (R10: killed the per-wave B re-read); 32 rows/wave.

template <bool RELU, bool HEAD>
__global__ __launch_bounds__(256) void sage_mfma_kernel(
    const unsigned short* __restrict__ Acat, const unsigned short* __restrict__ WT,
    const float* __restrict__ bias, unsigned short* __restrict__ hout, int out_stride,
    const float* __restrict__ Wfc, const float* __restrict__ bfc,
    float* __restrict__ outf, int nnodes) {

    __shared__ unsigned short Blds[128 * 256];   // 64KB, 16B-unit swizzle: c ^= row&7
    const int tid = threadIdx.x;

    {   // stage WT -> LDS (coalesced global, swizzled LDS)
        const short8* wsrc = reinterpret_cast<const short8*>(WT);
#pragma unroll
        for (int it = 0; it < 16; ++it) {
            int u = it * 256 + tid;                // 16B unit: 4096 total
            int row = u >> 5, c = u & 31;
            int cs = c ^ (row & 7);
            *reinterpret_cast<short8*>(
                reinterpret_cast<char*>(Blds) + row * 512 + cs * 16) = wsrc[u];
        }
    }
    __syncthreads();

    const int w = tid >> 6, l = tid & 63;
    const int r16 = l & 15, g = l >> 4;
    const int rowbase = blockIdx.x * 128 + w * 32;

    f32x4 acc[2][8];
#pragma unroll
    for (int j = 0; j < 8; ++j) {
        float bj = bias[j * 16 + r16];
        acc[0][j] = (f32x4){bj, bj, bj, bj};
        acc[1][j] = (f32x4){bj, bj, bj, bj};
    }

    const unsigned short* ap0 = Acat + (size_t)(rowbase + r16) * 256 + g * 8;
    const unsigned short* ap1 = ap0 + 16 * 256;

#pragma unroll
    for (int ks = 0; ks < 8; ++ks) {
        const short8 a0 = *reinterpret_cast<const short8*>(ap0 + ks * 32);
        const short8 a1 = *reinterpret_cast<const short8*>(ap1 + ks * 32);
        const int cs = ((ks * 4 + g) ^ (r16 & 7)) * 16;
#pragma unroll
        for (int j = 0; j < 8; ++j) {
            const short8 b = *reinterpret_cast<const short8*>(
                reinterpret_cast<const char*>(Blds) + (j * 16 + r16) * 512 + cs);
            acc[0][j] = __builtin_amdgcn_mfma_f32_16x16x32_bf16(a0, b, acc[0][j], 0, 0, 0);
            acc[1][j] = __builtin_amdgcn_mfma_f32_16x16x32_bf16(a1, b, acc[1][j], 0, 0, 0);
        }
    }

#pragma unroll
    for (int rb = 0; rb < 2; ++rb) {
        float ss[4] = {0.f, 0.f, 0.f, 0.f};
#pragma unroll
        for (int j = 0; j < 8; ++j)
#pragma unroll
            for (int i = 0; i < 4; ++i) ss[i] += acc[rb][j][i] * acc[rb][j][i];
#pragma unroll
        for (int m = 1; m < 16; m <<= 1)
#pragma unroll
            for (int i = 0; i < 4; ++i) ss[i] += __shfl_xor(ss[i], m, 64);

        if (!HEAD) {
#pragma unroll
            for (int i = 0; i < 4; ++i) {
                int row = rowbase + rb * 16 + g * 4 + i;
                if (row >= nnodes) continue;
                float sc = 1.0f / fmaxf(sqrtf(ss[i]), 1e-12f);
#pragma unroll
                for (int j = 0; j < 8; ++j) {
                    float v = acc[rb][j][i] * sc;
                    if (RELU) v = fmaxf(v, 0.f);
                    hout[(size_t)row * out_stride + j * 16 + r16] = f2b(v);
                }
            }
        } else {
            float w0[8], w1[8];
#pragma unroll
            for (int j = 0; j < 8; ++j) {
                const float2 wv = *reinterpret_cast<const float2*>(Wfc + (j * 16 + r16) * 2);
                w0[j] = wv.x; w1[j] = wv.y;
            }
            const float b0 = bfc[0], b1 = bfc[1];
#pragma unroll
            for (int i = 0; i < 4; ++i) {
                float sc = 1.0f / fmaxf(sqrtf(ss[i]), 1e-12f);
                float l0 = 0.f, l1 = 0.f;
#pragma unroll
                for (int j = 0; j < 8; ++j) {
                    float v = acc[rb][j][i] * sc;
                    l0 = fmaf(v, w0[j], l0);
                    l1 = fmaf(v, w1[j], l1);
                }
#pragma unroll
                for (int m = 1; m < 16; m <<= 1) {
                    l0 += __shfl_xor(l0, m, 64);
                    l1 += __shfl_xor(l1, m, 64);
                }
                int row = rowbase + rb * 16 + g * 4 + i;
                if (r16 == 0 && row < nnodes) {
                    float d0 = l0 + b0, d1 = l1 + b1;
                    float mx = fmaxf(d0, d1);
                    float e0 = expf(d0 - mx), e1 = expf(d1 - mx);
                    float inv = 1.0f / (e0 + e1);
                    outf[(size_t)row * 2]     = e0 * inv;
                    outf[(size_t)row * 2 + 1] = e1 * inv;
                }
            }
        }
    }
}

// ---------------- launch ----------------

extern "C" void kernel_launch(void* const* d_in, const int* in_sizes, int n_in,
                              void* d_out, int out_size, void* d_ws, size_t ws_size,
                              hipStream_t stream) {
    const float* x   = (const float*)d_in[0];
    const int*   ei  = (const int*)d_in[1];
    const float* W1l = (const float*)d_in[2];
    const float* b1l = (const float*)d_in[3];
    const float* W1r = (const float*)d_in[4];
    const float* W2l = (const float*)d_in[5];
    const float* b2l = (const float*)d_in[6];
    const float* W2r = (const float*)d_in[7];
    const float* Wfc = (const float*)d_in[8];
    const float* bfc = (const float*)d_in[9];

    const int N = in_sizes[0] / D;
    const int E = in_sizes[1] / 2;
    const int* src = ei;        // edge_index[0]
    const int* dst = ei + E;    // edge_index[1]
    const int NBC = (N + (1 << CBITS) - 1) >> CBITS;     // coarse buckets (196), <=256

    // workspace: bf16 feature tables first (16B aligned), ints after
    unsigned short* Acat1 = (unsigned short*)d_ws;        // N x 256 : [agg1 | xb]
    unsigned short* Acat2 = Acat1 + (size_t)N * 256;      // N x 256 : [agg2 | h1]
    int* staging          = (int*)Acat2;                  // E ints (dead until mfma1; consumed before)
    unsigned short* WT1   = Acat2 + (size_t)N * 256;      // 128 x 256
    unsigned short* WT2   = WT1 + 128 * 256;              // 128 x 256
    int* bucketCnt  = (int*)(WT2 + 128 * 256);            // 256 } zeroed together (512 ints)
    int* cursorA    = bucketCnt + 256;                    // 256 }
    int* offsets    = cursorA + 256;                      // N+1
    int* csr        = offsets + N + 1;                    // E

    const int nCast = (N * 16 + 255) / 256;

    // prep: cast x into Acat1[:,128:], transpose weights, zero counters, offsets[N]=E
    prep_kernel<<<nCast + 256 + 1, 256, 0, stream>>>(
        x, Acat1, nCast, N * 16, W1l, W1r, W2l, W2r, WT1, WT2,
        (int4*)bucketCnt, offsets, N, E);

    // CSR build: zero per-edge global atomics, scans inlined, packed staging
    bucket_count_kernel<<<(E + 4095) / 4096, 256, 0, stream>>>(dst, bucketCnt, E);
    bin_coarse_kernel<<<(E + 4095) / 4096, 256, 0, stream>>>(src, dst, bucketCnt, cursorA, staging, E);
    bucket_build_kernel<<<NBC, 256, 0, stream>>>(staging, bucketCnt, offsets, csr, N);

    // layer 1: agg(xb) -> Acat1[:,0:128]; h1 = relu(l2norm(...)) -> Acat2[:,128:256]
    aggregate_kernel<<<(N + 15) / 16, 256, 0, stream>>>(Acat1 + 128, offsets, csr, Acat1, N);
    sage_mfma_kernel<true, false><<<(N + 127) / 128, 256, 0, stream>>>(
        Acat1, WT1, b1l, Acat2 + 128, 256, nullptr, nullptr, nullptr, N);

    // layer 2: agg(h1) -> Acat2[:,0:128]; head fused: softmax(l2norm(...)@Wfc+bfc) -> d_out
    aggregate_kernel<<<(N + 15) / 16, 256, 0, stream>>>(Acat2 + 128, offsets, csr, Acat2, N);
    sage_mfma_kernel<false, true><<<(N + 127) / 128, 256, 0, stream>>>(
        Acat2, WT2, b2l, nullptr, 0, Wfc, bfc, (float*)d_out, N);
}